// Round 5
// baseline (1617.362 us; speedup 1.0000x reference)
//
#include <hip/hip_runtime.h>
#include <hip/hip_bf16.h>

typedef __attribute__((ext_vector_type(4))) float f32x4;
typedef __attribute__((ext_vector_type(2))) unsigned int u32x2;
typedef __attribute__((ext_vector_type(4))) unsigned int u32x4;
typedef __attribute__((ext_vector_type(8))) short s16x8;

#define BB 16
#define TT 48
#define NV 207
#define FF 512
#define MTOT (BB*TT*NV)   // 158976

static __device__ __forceinline__ unsigned short f2b(float f) {
  unsigned int u = __builtin_bit_cast(unsigned int, f);
  u += 0x7fffu + ((u >> 16) & 1u);
  return (unsigned short)(u >> 16);
}
static __device__ __forceinline__ unsigned int pk2(float a, float b) {
  return (unsigned int)f2b(a) | ((unsigned int)f2b(b) << 16);
}

typedef const __attribute__((address_space(1))) unsigned char* gp_t;
typedef __attribute__((address_space(3))) unsigned char* lp_t;
static __device__ __forceinline__ void gld16(const void* g, void* l) {
  __builtin_amdgcn_global_load_lds((gp_t)g, (lp_t)l, 16, 0, 0);
}

// ---------------------------------------------------------------------------
// K0: weights -> transposed [n][k] bf16, pre-swizzled (chunk ^= row&7 on low3)
// ---------------------------------------------------------------------------
__global__ __launch_bounds__(256)
void prep_weights(const float* __restrict__ Wq, const float* __restrict__ Wk,
                  const float* __restrict__ Wv, const float* __restrict__ W1,
                  const float* __restrict__ W2, const float* __restrict__ bq,
                  const float* __restrict__ bk, const float* __restrict__ bv,
                  unsigned short* __restrict__ wqkv, unsigned short* __restrict__ w1t,
                  unsigned short* __restrict__ w2t, float* __restrict__ bqkv)
{
  int tid = blockIdx.x * 256 + threadIdx.x;
  if (tid < 1536) {
    const float* bs = tid < 512 ? bq : (tid < 1024 ? bk : bv);
    bqkv[tid] = bs[tid & 511];
  }
  if (tid >= 2560 * 64) return;
  int row = tid >> 6, c = tid & 63;
  const float* src; unsigned short* dst; int ncol;
  if (row < 1536)      { src = (row < 512 ? Wq : (row < 1024 ? Wk : Wv)); ncol = row & 511; dst = wqkv + row * 512; }
  else if (row < 2048) { src = W1; ncol = row - 1536; dst = w1t + (row - 1536) * 512; }
  else                 { src = W2; ncol = row - 2048; dst = w2t + (row - 2048) * 512; }
  int cs = c ^ (row & 7);             // flips only low3 of chunk index
  unsigned short* d = dst + cs * 8;
  #pragma unroll
  for (int j = 0; j < 8; j++)
    d[j] = f2b(src[(c * 8 + j) * 512 + ncol]);
}

// ---------------------------------------------------------------------------
// K0b: x fp32 -> bf16, row-swizzled (chunk ^= m&7), one wave per row
// ---------------------------------------------------------------------------
__global__ __launch_bounds__(256)
void xcast_k(const float* __restrict__ x, unsigned short* __restrict__ xb)
{
  int tid = blockIdx.x * 256 + threadIdx.x;
  int m = tid >> 6, c = tid & 63;
  const f32x4* src = (const f32x4*)(x + (size_t)m * 512 + c * 8);
  f32x4 a = src[0], b = src[1];
  u32x4 v = { pk2(a[0], a[1]), pk2(a[2], a[3]), pk2(b[0], b[1]), pk2(b[2], b[3]) };
  int p = c ^ (m & 7);
  *(u32x4*)(xb + (size_t)m * 512 + p * 8) = v;
}

// ---------------------------------------------------------------------------
// K1/K3/K4: 128x128xK GEMM, BK=64, 4 waves, mfma_f32_16x16x32_bf16
//  A bf16 pre-swizzled rows (1024 B/row), global_load_lds linear
//  EPI 0: +bias      EPI 1: gelu(+bias)      EPI 2: +bias +resid(fp32)
//  Output bf16, row-swizzled (col ^= (m&7)<<3)
// ---------------------------------------------------------------------------
static __device__ __forceinline__ float gelu_f(float v) {
  return 0.5f * v * (1.0f + erff(v * 0.70710678118654752f));
}

template<int EPI>
__global__ __launch_bounds__(256)
void gemm_k(const void* __restrict__ Aptr, const unsigned short* __restrict__ Bt,
            const float* __restrict__ bias, const float* __restrict__ resid,
            unsigned short* __restrict__ Out, int Ncols, int ntiles)
{
  __shared__ __align__(16) unsigned char lds[32768];
  unsigned char* Asb = lds;
  unsigned char* Bsb = lds + 16384;
  const int tid = threadIdx.x;
  const int w = tid >> 6, l = tid & 63;
  const int mtile = blockIdx.x / ntiles;
  const int ntile = blockIdx.x - mtile * ntiles;
  const int m0 = mtile * 128;
  const int n0 = ntile * 128;
  const int wr = (w >> 1) * 64, wc = (w & 1) * 64;

  f32x4 acc[4][4];
  #pragma unroll
  for (int i = 0; i < 4; i++)
    #pragma unroll
    for (int j = 0; j < 4; j++)
      acc[i][j] = (f32x4){0.f, 0.f, 0.f, 0.f};

  for (int kk = 0; kk < 512; kk += 64) {
    {
      const unsigned char* Ab = (const unsigned char*)Aptr;
      #pragma unroll
      for (int j = 0; j < 4; j++) {
        int rb = j * 32 + w * 8;
        gld16(Ab + (size_t)(m0 + rb + (l >> 3)) * 1024 + kk * 2 + (l & 7) * 16,
              Asb + rb * 128);
      }
    }
    {
      const unsigned char* Bb = (const unsigned char*)Bt;
      #pragma unroll
      for (int j = 0; j < 4; j++) {
        int rb = j * 32 + w * 8;
        gld16(Bb + (size_t)(n0 + rb + (l >> 3)) * 1024 + kk * 2 + (l & 7) * 16,
              Bsb + rb * 128);
      }
    }
    __syncthreads();
    #pragma unroll
    for (int ks = 0; ks < 2; ks++) {
      s16x8 af[4], bfr[4];
      #pragma unroll
      for (int mt = 0; mt < 4; mt++) {
        int r = wr + mt * 16 + (l & 15);
        int c = (l >> 4) + ks * 4;
        af[mt] = *(const s16x8*)(Asb + r * 128 + ((c ^ (r & 7)) * 16));
      }
      #pragma unroll
      for (int nt = 0; nt < 4; nt++) {
        int r = wc + nt * 16 + (l & 15);
        int c = (l >> 4) + ks * 4;
        bfr[nt] = *(const s16x8*)(Bsb + r * 128 + ((c ^ (r & 7)) * 16));
      }
      #pragma unroll
      for (int mt = 0; mt < 4; mt++)
        #pragma unroll
        for (int nt = 0; nt < 4; nt++)
          acc[mt][nt] = __builtin_amdgcn_mfma_f32_16x16x32_bf16(af[mt], bfr[nt], acc[mt][nt], 0, 0, 0);
    }
    __syncthreads();
  }

  #pragma unroll
  for (int mt = 0; mt < 4; mt++)
    #pragma unroll
    for (int nt = 0; nt < 4; nt++)
      #pragma unroll
      for (int rg = 0; rg < 4; rg++) {
        int m = m0 + wr + mt * 16 + ((l >> 4) << 2) + rg;
        int n = n0 + wc + nt * 16 + (l & 15);
        float v = acc[mt][nt][rg] + bias[n];
        if constexpr (EPI == 1) v = gelu_f(v);
        if constexpr (EPI == 2) v += resid[(size_t)m * 512 + n];
        int ns = n ^ ((m & 7) << 3);
        Out[(size_t)m * Ncols + ns] = f2b(v);
      }
}

// ---------------------------------------------------------------------------
// K2: causal attention over T=48, d=64, per (b, vertex, head)
//  block = 256 thr = 4 waves, wave = 1 head; 2 blocks cover 8 heads
// ---------------------------------------------------------------------------
__global__ __launch_bounds__(256)
void attn_k(const unsigned short* __restrict__ qkv, unsigned short* __restrict__ obuf)
{
  __shared__ __align__(16) unsigned char lds[81920];     // 4 waves * 20 KB
  const int tid = threadIdx.x, w = tid >> 6, l = tid & 63;
  const int bid = blockIdx.x;
  const int hg = bid & 1;
  const int bn = bid >> 1;
  const int b = bn / NV, n = bn - b * NV;
  const int head = hg * 4 + w;
  unsigned char* base = lds + w * 20480;
  unsigned char* qsb = base;               // q  [48][64] bf16 swz
  unsigned char* ksb = base + 6144;        // k  [48][64] swz, later P[48][64]
  unsigned char* vtb = base + 12288;       // v^T [64][64] swz (cols 48..63 zero)
  const unsigned char* qb = (const unsigned char*)qkv;
  const int mbase = (b * TT) * NV + n;     // m = mbase + t*207

  { // zero v^T pad (logical chunks 6,7 = cols 48..63), row dd = l
    u32x4 z = {0, 0, 0, 0};
    *(u32x4*)(vtb + l * 128 + ((6 ^ (l & 7)) * 16)) = z;
    *(u32x4*)(vtb + l * 128 + ((7 ^ (l & 7)) * 16)) = z;
  }
  #pragma unroll
  for (int j = 0; j < 6; j++) {            // q,k: 8 rows per issue
    int t = j * 8 + (l >> 3);
    int m = mbase + t * NV;
    size_t rowb = (size_t)m * 3072;
    int slot = (l & 7) ^ (t & 7) ^ (m & 7);
    gld16(qb + rowb + head * 128 + slot * 16,        qsb + j * 1024);
    gld16(qb + rowb + 1024 + head * 128 + slot * 16, ksb + j * 1024);
  }
  #pragma unroll
  for (int j = 0; j < 6; j++) {            // v: register transpose into vtb
    int s = j * 8 + (l >> 3);
    int m = mbase + s * NV;
    int c = l & 7;
    u32x4 g = *(const u32x4*)(qb + (size_t)m * 3072 + 2048 + head * 128 + ((c ^ (m & 7)) * 16));
    #pragma unroll
    for (int e = 0; e < 8; e++) {
      unsigned int word = g[e >> 1];
      unsigned short hv = (e & 1) ? (unsigned short)(word >> 16) : (unsigned short)(word & 0xffffu);
      int dd = c * 8 + e;
      *(unsigned short*)(vtb + dd * 128 + (((s >> 3) ^ (dd & 7)) * 16) + (s & 7) * 2) = hv;
    }
  }
  __syncthreads();

  // ---- S = q k^T  (3x3 tiles, K=64) ----
  s16x8 qf[3][2], kf[3][2];
  #pragma unroll
  for (int mt = 0; mt < 3; mt++)
    #pragma unroll
    for (int ksi = 0; ksi < 2; ksi++) {
      int r = mt * 16 + (l & 15);
      int c = (l >> 4) + ksi * 4;
      qf[mt][ksi] = *(const s16x8*)(qsb + r * 128 + ((c ^ (r & 7)) * 16));
      kf[mt][ksi] = *(const s16x8*)(ksb + r * 128 + ((c ^ (r & 7)) * 16));
    }
  f32x4 sacc[3][3];
  #pragma unroll
  for (int i = 0; i < 3; i++)
    #pragma unroll
    for (int j = 0; j < 3; j++)
      sacc[i][j] = (f32x4){0.f, 0.f, 0.f, 0.f};
  #pragma unroll
  for (int ksi = 0; ksi < 2; ksi++)
    #pragma unroll
    for (int mt = 0; mt < 3; mt++)
      #pragma unroll
      for (int nt = 0; nt < 3; nt++)
        sacc[mt][nt] = __builtin_amdgcn_mfma_f32_16x16x32_bf16(qf[mt][ksi], kf[nt][ksi], sacc[mt][nt], 0, 0, 0);

  // ---- P region aliases ksb (k frags already in regs): zero pad cols 48..63
  if (l < 48) {
    u32x4 z = {0, 0, 0, 0};
    *(u32x4*)(ksb + l * 128 + ((6 ^ (l & 7)) * 16)) = z;
    *(u32x4*)(ksb + l * 128 + ((7 ^ (l & 7)) * 16)) = z;
  }

  // ---- masked softmax over s (rows t), wave-parallel, write P bf16 ----
  const int s0 = l & 15;
  #pragma unroll
  for (int mt = 0; mt < 3; mt++) {
    #pragma unroll
    for (int rg = 0; rg < 4; rg++) {
      int t = mt * 16 + ((l >> 4) << 2) + rg;
      float v0 = sacc[mt][0][rg] * 0.125f;
      float v1 = sacc[mt][1][rg] * 0.125f;
      float v2 = sacc[mt][2][rg] * 0.125f;
      if (s0 > t)      v0 = -3.0e38f;
      if (s0 + 16 > t) v1 = -3.0e38f;
      if (s0 + 32 > t) v2 = -3.0e38f;
      float mx = fmaxf(v0, fmaxf(v1, v2));
      #pragma unroll
      for (int d = 1; d < 16; d <<= 1) mx = fmaxf(mx, __shfl_xor(mx, d, 64));
      float e0 = __expf(v0 - mx), e1 = __expf(v1 - mx), e2 = __expf(v2 - mx);
      float sm = e0 + e1 + e2;
      #pragma unroll
      for (int d = 1; d < 16; d <<= 1) sm += __shfl_xor(sm, d, 64);
      float inv = 1.0f / sm;
      float pv[3] = { e0 * inv, e1 * inv, e2 * inv };
      #pragma unroll
      for (int nt = 0; nt < 3; nt++) {
        int s = nt * 16 + s0;
        *(unsigned short*)(ksb + t * 128 + (((s >> 3) ^ (t & 7)) * 16) + (s & 7) * 2) = f2b(pv[nt]);
      }
    }
  }
  __syncthreads();

  // ---- O = P v  (3x4 tiles, K=64 zero-padded) ----
  s16x8 pf[3][2], vf[4][2];
  #pragma unroll
  for (int ksi = 0; ksi < 2; ksi++) {
    int c = (l >> 4) + ksi * 4;
    #pragma unroll
    for (int mt = 0; mt < 3; mt++) {
      int r = mt * 16 + (l & 15);
      pf[mt][ksi] = *(const s16x8*)(ksb + r * 128 + ((c ^ (r & 7)) * 16));
    }
    #pragma unroll
    for (int nt = 0; nt < 4; nt++) {
      int r = nt * 16 + (l & 15);
      vf[nt][ksi] = *(const s16x8*)(vtb + r * 128 + ((c ^ (r & 7)) * 16));
    }
  }
  f32x4 oacc[3][4];
  #pragma unroll
  for (int i = 0; i < 3; i++)
    #pragma unroll
    for (int j = 0; j < 4; j++)
      oacc[i][j] = (f32x4){0.f, 0.f, 0.f, 0.f};
  #pragma unroll
  for (int ksi = 0; ksi < 2; ksi++)
    #pragma unroll
    for (int mt = 0; mt < 3; mt++)
      #pragma unroll
      for (int nt = 0; nt < 4; nt++)
        oacc[mt][nt] = __builtin_amdgcn_mfma_f32_16x16x32_bf16(pf[mt][ksi], vf[nt][ksi], oacc[mt][nt], 0, 0, 0);

  #pragma unroll
  for (int mt = 0; mt < 3; mt++)
    #pragma unroll
    for (int nt = 0; nt < 4; nt++)
      #pragma unroll
      for (int rg = 0; rg < 4; rg++) {
        int t = mt * 16 + ((l >> 4) << 2) + rg;
        int m = mbase + t * NV;
        int col = head * 64 + nt * 16 + (l & 15);
        int ns = col ^ ((m & 7) << 3);
        obuf[(size_t)m * 512 + ns] = f2b(oacc[mt][nt][rg]);
      }
}

// ---------------------------------------------------------------------------
// K5: LayerNorm over F=512, wave per row, fp32 out
// ---------------------------------------------------------------------------
__global__ __launch_bounds__(256)
void ln_k(const unsigned short* __restrict__ h, const float* __restrict__ gamma,
          const float* __restrict__ beta, float* __restrict__ out)
{
  const int tid = threadIdx.x, l = tid & 63;
  const int m = blockIdx.x * 4 + (tid >> 6);
  const unsigned char* hb = (const unsigned char*)h;
  u32x4 raw = *(const u32x4*)(hb + (size_t)m * 1024 + ((l ^ (m & 7)) * 16));
  float f[8];
  float sum = 0.f, sq = 0.f;
  #pragma unroll
  for (int i = 0; i < 4; i++) {
    unsigned int u = raw[i];
    float a = __builtin_bit_cast(float, u << 16);
    float c = __builtin_bit_cast(float, u & 0xffff0000u);
    f[2 * i] = a; f[2 * i + 1] = c;
    sum += a + c; sq += a * a + c * c;
  }
  #pragma unroll
  for (int d = 1; d < 64; d <<= 1) { sum += __shfl_xor(sum, d, 64); sq += __shfl_xor(sq, d, 64); }
  float mean = sum * (1.0f / 512.0f);
  float var = sq * (1.0f / 512.0f) - mean * mean;
  float rs = rsqrtf(var + 1e-5f);
  int cb = l * 8;
  f32x4 o1, o2;
  #pragma unroll
  for (int j = 0; j < 4; j++) o1[j] = gamma[cb + j] * ((f[j] - mean) * rs) + beta[cb + j];
  #pragma unroll
  for (int j = 0; j < 4; j++) o2[j] = gamma[cb + 4 + j] * ((f[4 + j] - mean) * rs) + beta[cb + 4 + j];
  *(f32x4*)(out + (size_t)m * 512 + cb) = o1;
  *(f32x4*)(out + (size_t)m * 512 + cb + 4) = o2;
}

// ---------------------------------------------------------------------------
extern "C" void kernel_launch(void* const* d_in, const int* in_sizes, int n_in,
                              void* d_out, int out_size, void* d_ws, size_t ws_size,
                              hipStream_t stream)
{
  const float* x     = (const float*)d_in[0];
  const float* Wq    = (const float*)d_in[1];
  const float* bq    = (const float*)d_in[2];
  const float* Wk    = (const float*)d_in[3];
  const float* bk    = (const float*)d_in[4];
  const float* Wv    = (const float*)d_in[5];
  const float* bv    = (const float*)d_in[6];
  const float* W1    = (const float*)d_in[7];
  const float* b1    = (const float*)d_in[8];
  const float* W2    = (const float*)d_in[9];
  const float* b2    = (const float*)d_in[10];
  const float* gamma = (const float*)d_in[11];
  const float* beta  = (const float*)d_in[12];
  float* out = (float*)d_out;

  unsigned char* ws = (unsigned char*)d_ws;
  unsigned short* wqkv = (unsigned short*)ws;               // 1,572,864 B
  unsigned short* w1t  = (unsigned short*)(ws + 1572864);   //   524,288 B
  unsigned short* w2t  = (unsigned short*)(ws + 2097152);   //   524,288 B
  float*          bqkv = (float*)        (ws + 2621440);    //     6,144 B
  unsigned short* qkvb = (unsigned short*)(ws + 2627584);   // 488,374,272 B (also h1)
  unsigned short* obuf = (unsigned short*)(ws + 491001856); // 162,791,424 B (xb, then o/h2)

  unsigned short* xb = obuf;  // x bf16 lives only until attn overwrites obuf

  prep_weights<<<640, 256, 0, stream>>>(Wq, Wk, Wv, W1, W2, bq, bk, bv, wqkv, w1t, w2t, bqkv);
  // x fp32 -> bf16 swizzled rows (one-time cast; saves 12x fp32 re-read in QKV)
  xcast_k<<<MTOT / 4, 256, 0, stream>>>(x, xb);
  // QKV: [M,512] bf16 xb @ [512,1536] -> qkv bf16 (swz rows)
  gemm_k<0><<<1242 * 12, 256, 0, stream>>>((const void*)xb, wqkv, bqkv, nullptr, qkvb, 1536, 12);
  // attention -> o bf16 (swz rows; overwrites xb which is now dead)
  attn_k<<<3312 * 2, 256, 0, stream>>>(qkvb, obuf);
  // FFN1: gelu(o@W1+b1) -> h1 (aliases qkv region)
  gemm_k<1><<<1242 * 4, 256, 0, stream>>>((const void*)obuf, w1t, b1, nullptr, qkvb, 512, 4);
  // FFN2: h1@W2+b2+x -> h2 (aliases o region)
  gemm_k<2><<<1242 * 4, 256, 0, stream>>>((const void*)qkvb, w2t, b2, x, obuf, 512, 4);
  // LayerNorm -> fp32 out
  ln_k<<<MTOT / 4, 256, 0, stream>>>(obuf, gamma, beta, out);
}

// Round 7
// 1580.086 us; speedup vs baseline: 1.0236x; 1.0236x over previous
//
#include <hip/hip_runtime.h>
#include <hip/hip_bf16.h>

typedef __attribute__((ext_vector_type(4))) float f32x4;
typedef __attribute__((ext_vector_type(2))) unsigned int u32x2;
typedef __attribute__((ext_vector_type(4))) unsigned int u32x4;
typedef __attribute__((ext_vector_type(8))) short s16x8;

#define BB 16
#define TT 48
#define NV 207
#define FF 512
#define MTOT (BB*TT*NV)   // 158976

static __device__ __forceinline__ unsigned short f2b(float f) {
  unsigned int u = __builtin_bit_cast(unsigned int, f);
  u += 0x7fffu + ((u >> 16) & 1u);
  return (unsigned short)(u >> 16);
}
static __device__ __forceinline__ unsigned int pk2(float a, float b) {
  return (unsigned int)f2b(a) | ((unsigned int)f2b(b) << 16);
}

typedef const __attribute__((address_space(1))) unsigned char* gp_t;
typedef __attribute__((address_space(3))) unsigned char* lp_t;
static __device__ __forceinline__ void gld16(const void* g, void* l) {
  __builtin_amdgcn_global_load_lds((gp_t)g, (lp_t)l, 16, 0, 0);
}

// ---------------------------------------------------------------------------
// K0: weights -> transposed [n][k] bf16, pre-swizzled (chunk ^= row&7 on low3)
// ---------------------------------------------------------------------------
__global__ __launch_bounds__(256)
void prep_weights(const float* __restrict__ Wq, const float* __restrict__ Wk,
                  const float* __restrict__ Wv, const float* __restrict__ W1,
                  const float* __restrict__ W2, const float* __restrict__ bq,
                  const float* __restrict__ bk, const float* __restrict__ bv,
                  unsigned short* __restrict__ wqkv, unsigned short* __restrict__ w1t,
                  unsigned short* __restrict__ w2t, float* __restrict__ bqkv)
{
  int tid = blockIdx.x * 256 + threadIdx.x;
  if (tid < 1536) {
    const float* bs = tid < 512 ? bq : (tid < 1024 ? bk : bv);
    bqkv[tid] = bs[tid & 511];
  }
  if (tid >= 2560 * 64) return;
  int row = tid >> 6, c = tid & 63;
  const float* src; unsigned short* dst; int ncol;
  if (row < 1536)      { src = (row < 512 ? Wq : (row < 1024 ? Wk : Wv)); ncol = row & 511; dst = wqkv + row * 512; }
  else if (row < 2048) { src = W1; ncol = row - 1536; dst = w1t + (row - 1536) * 512; }
  else                 { src = W2; ncol = row - 2048; dst = w2t + (row - 2048) * 512; }
  int cs = c ^ (row & 7);             // flips only low3 of chunk index
  unsigned short* d = dst + cs * 8;
  #pragma unroll
  for (int j = 0; j < 8; j++)
    d[j] = f2b(src[(c * 8 + j) * 512 + ncol]);
}

// ---------------------------------------------------------------------------
// K0b: x fp32 -> bf16, row-swizzled (chunk ^= m&7), one wave per row
// ---------------------------------------------------------------------------
__global__ __launch_bounds__(256)
void xcast_k(const float* __restrict__ x, unsigned short* __restrict__ xb)
{
  int tid = blockIdx.x * 256 + threadIdx.x;
  int m = tid >> 6, c = tid & 63;
  const f32x4* src = (const f32x4*)(x + (size_t)m * 512 + c * 8);
  f32x4 a = src[0], b = src[1];
  u32x4 v = { pk2(a[0], a[1]), pk2(a[2], a[3]), pk2(b[0], b[1]), pk2(b[2], b[3]) };
  int p = c ^ (m & 7);
  *(u32x4*)(xb + (size_t)m * 512 + p * 8) = v;
}

// ---------------------------------------------------------------------------
// K1/K3/K4: 128x128xK GEMM, BK=64, 4 waves, mfma_f32_16x16x32_bf16
//  A bf16 pre-swizzled rows (1024 B/row), global_load_lds linear
//  EPI 0: +bias      EPI 1: gelu(+bias)      EPI 2: +bias +resid(fp32)
//  Output bf16, row-swizzled (col ^= (m&7)<<3)
//  T1: bijective XCD swizzle (grid % 8 == 0 for all launches)
// ---------------------------------------------------------------------------
static __device__ __forceinline__ float gelu_f(float v) {
  return 0.5f * v * (1.0f + erff(v * 0.70710678118654752f));
}

template<int EPI>
__global__ __launch_bounds__(256)
void gemm_k(const void* __restrict__ Aptr, const unsigned short* __restrict__ Bt,
            const float* __restrict__ bias, const float* __restrict__ resid,
            unsigned short* __restrict__ Out, int Ncols, int ntiles)
{
  __shared__ __align__(16) unsigned char lds[32768];
  unsigned char* Asb = lds;
  unsigned char* Bsb = lds + 16384;
  const int tid = threadIdx.x;
  const int w = tid >> 6, l = tid & 63;
  // T1: consecutive logical blocks -> same XCD (bid%8 is the HW XCD slot)
  const int nwg = gridDim.x;
  const int cpx = nwg >> 3;
  const int bid = (blockIdx.x & 7) * cpx + (blockIdx.x >> 3);
  const int mtile = bid / ntiles;
  const int ntile = bid - mtile * ntiles;
  const int m0 = mtile * 128;
  const int n0 = ntile * 128;
  const int wr = (w >> 1) * 64, wc = (w & 1) * 64;

  f32x4 acc[4][4];
  #pragma unroll
  for (int i = 0; i < 4; i++)
    #pragma unroll
    for (int j = 0; j < 4; j++)
      acc[i][j] = (f32x4){0.f, 0.f, 0.f, 0.f};

  for (int kk = 0; kk < 512; kk += 64) {
    {
      const unsigned char* Ab = (const unsigned char*)Aptr;
      #pragma unroll
      for (int j = 0; j < 4; j++) {
        int rb = j * 32 + w * 8;
        gld16(Ab + (size_t)(m0 + rb + (l >> 3)) * 1024 + kk * 2 + (l & 7) * 16,
              Asb + rb * 128);
      }
    }
    {
      const unsigned char* Bb = (const unsigned char*)Bt;
      #pragma unroll
      for (int j = 0; j < 4; j++) {
        int rb = j * 32 + w * 8;
        gld16(Bb + (size_t)(n0 + rb + (l >> 3)) * 1024 + kk * 2 + (l & 7) * 16,
              Bsb + rb * 128);
      }
    }
    __syncthreads();
    #pragma unroll
    for (int ks = 0; ks < 2; ks++) {
      s16x8 af[4], bfr[4];
      #pragma unroll
      for (int mt = 0; mt < 4; mt++) {
        int r = wr + mt * 16 + (l & 15);
        int c = (l >> 4) + ks * 4;
        af[mt] = *(const s16x8*)(Asb + r * 128 + ((c ^ (r & 7)) * 16));
      }
      #pragma unroll
      for (int nt = 0; nt < 4; nt++) {
        int r = wc + nt * 16 + (l & 15);
        int c = (l >> 4) + ks * 4;
        bfr[nt] = *(const s16x8*)(Bsb + r * 128 + ((c ^ (r & 7)) * 16));
      }
      #pragma unroll
      for (int mt = 0; mt < 4; mt++)
        #pragma unroll
        for (int nt = 0; nt < 4; nt++)
          acc[mt][nt] = __builtin_amdgcn_mfma_f32_16x16x32_bf16(af[mt], bfr[nt], acc[mt][nt], 0, 0, 0);
    }
    __syncthreads();
  }

  #pragma unroll
  for (int mt = 0; mt < 4; mt++)
    #pragma unroll
    for (int nt = 0; nt < 4; nt++)
      #pragma unroll
      for (int rg = 0; rg < 4; rg++) {
        int m = m0 + wr + mt * 16 + ((l >> 4) << 2) + rg;
        int n = n0 + wc + nt * 16 + (l & 15);
        float v = acc[mt][nt][rg] + bias[n];
        if constexpr (EPI == 1) v = gelu_f(v);
        if constexpr (EPI == 2) v += resid[(size_t)m * 512 + n];
        int ns = n ^ ((m & 7) << 3);
        Out[(size_t)m * Ncols + ns] = f2b(v);
      }
}

// ---------------------------------------------------------------------------
// K2: causal attention over T=48, d=64, per (b, vertex, head)
//  block = 256 thr = 4 waves, wave = 1 head; 2 blocks cover 8 heads
// ---------------------------------------------------------------------------
__global__ __launch_bounds__(256)
void attn_k(const unsigned short* __restrict__ qkv, unsigned short* __restrict__ obuf)
{
  __shared__ __align__(16) unsigned char lds[81920];     // 4 waves * 20 KB
  const int tid = threadIdx.x, w = tid >> 6, l = tid & 63;
  const int bid = blockIdx.x;
  const int hg = bid & 1;
  const int bn = bid >> 1;
  const int b = bn / NV, n = bn - b * NV;
  const int head = hg * 4 + w;
  unsigned char* base = lds + w * 20480;
  unsigned char* qsb = base;               // q  [48][64] bf16 swz
  unsigned char* ksb = base + 6144;        // k  [48][64] swz, later P[48][64]
  unsigned char* vtb = base + 12288;       // v^T [64][64] swz (cols 48..63 zero)
  const unsigned char* qb = (const unsigned char*)qkv;
  const int mbase = (b * TT) * NV + n;     // m = mbase + t*207

  { // zero v^T pad (logical chunks 6,7 = cols 48..63), row dd = l
    u32x4 z = {0, 0, 0, 0};
    *(u32x4*)(vtb + l * 128 + ((6 ^ (l & 7)) * 16)) = z;
    *(u32x4*)(vtb + l * 128 + ((7 ^ (l & 7)) * 16)) = z;
  }
  #pragma unroll
  for (int j = 0; j < 6; j++) {            // q,k: 8 rows per issue
    int t = j * 8 + (l >> 3);
    int m = mbase + t * NV;
    size_t rowb = (size_t)m * 3072;
    int slot = (l & 7) ^ (t & 7) ^ (m & 7);
    gld16(qb + rowb + head * 128 + slot * 16,        qsb + j * 1024);
    gld16(qb + rowb + 1024 + head * 128 + slot * 16, ksb + j * 1024);
  }
  #pragma unroll
  for (int j = 0; j < 6; j++) {            // v: register transpose into vtb
    int s = j * 8 + (l >> 3);
    int m = mbase + s * NV;
    int c = l & 7;
    u32x4 g = *(const u32x4*)(qb + (size_t)m * 3072 + 2048 + head * 128 + ((c ^ (m & 7)) * 16));
    #pragma unroll
    for (int e = 0; e < 8; e++) {
      unsigned int word = g[e >> 1];
      unsigned short hv = (e & 1) ? (unsigned short)(word >> 16) : (unsigned short)(word & 0xffffu);
      int dd = c * 8 + e;
      *(unsigned short*)(vtb + dd * 128 + (((s >> 3) ^ (dd & 7)) * 16) + (s & 7) * 2) = hv;
    }
  }
  __syncthreads();

  // ---- S = q k^T  (3x3 tiles, K=64) ----
  s16x8 qf[3][2], kf[3][2];
  #pragma unroll
  for (int mt = 0; mt < 3; mt++)
    #pragma unroll
    for (int ksi = 0; ksi < 2; ksi++) {
      int r = mt * 16 + (l & 15);
      int c = (l >> 4) + ksi * 4;
      qf[mt][ksi] = *(const s16x8*)(qsb + r * 128 + ((c ^ (r & 7)) * 16));
      kf[mt][ksi] = *(const s16x8*)(ksb + r * 128 + ((c ^ (r & 7)) * 16));
    }
  f32x4 sacc[3][3];
  #pragma unroll
  for (int i = 0; i < 3; i++)
    #pragma unroll
    for (int j = 0; j < 3; j++)
      sacc[i][j] = (f32x4){0.f, 0.f, 0.f, 0.f};
  #pragma unroll
  for (int ksi = 0; ksi < 2; ksi++)
    #pragma unroll
    for (int mt = 0; mt < 3; mt++)
      #pragma unroll
      for (int nt = 0; nt < 3; nt++)
        sacc[mt][nt] = __builtin_amdgcn_mfma_f32_16x16x32_bf16(qf[mt][ksi], kf[nt][ksi], sacc[mt][nt], 0, 0, 0);

  // ---- P region aliases ksb (k frags already in regs): zero pad cols 48..63
  if (l < 48) {
    u32x4 z = {0, 0, 0, 0};
    *(u32x4*)(ksb + l * 128 + ((6 ^ (l & 7)) * 16)) = z;
    *(u32x4*)(ksb + l * 128 + ((7 ^ (l & 7)) * 16)) = z;
  }

  // ---- masked softmax over s (rows t), wave-parallel, write P bf16 ----
  const int s0 = l & 15;
  #pragma unroll
  for (int mt = 0; mt < 3; mt++) {
    #pragma unroll
    for (int rg = 0; rg < 4; rg++) {
      int t = mt * 16 + ((l >> 4) << 2) + rg;
      float v0 = sacc[mt][0][rg] * 0.125f;
      float v1 = sacc[mt][1][rg] * 0.125f;
      float v2 = sacc[mt][2][rg] * 0.125f;
      if (s0 > t)      v0 = -3.0e38f;
      if (s0 + 16 > t) v1 = -3.0e38f;
      if (s0 + 32 > t) v2 = -3.0e38f;
      float mx = fmaxf(v0, fmaxf(v1, v2));
      #pragma unroll
      for (int d = 1; d < 16; d <<= 1) mx = fmaxf(mx, __shfl_xor(mx, d, 64));
      float e0 = __expf(v0 - mx), e1 = __expf(v1 - mx), e2 = __expf(v2 - mx);
      float sm = e0 + e1 + e2;
      #pragma unroll
      for (int d = 1; d < 16; d <<= 1) sm += __shfl_xor(sm, d, 64);
      float inv = 1.0f / sm;
      float pv[3] = { e0 * inv, e1 * inv, e2 * inv };
      #pragma unroll
      for (int nt = 0; nt < 3; nt++) {
        int s = nt * 16 + s0;
        *(unsigned short*)(ksb + t * 128 + (((s >> 3) ^ (t & 7)) * 16) + (s & 7) * 2) = f2b(pv[nt]);
      }
    }
  }
  __syncthreads();

  // ---- O = P v  (3x4 tiles, K=64 zero-padded) ----
  s16x8 pf[3][2], vf[4][2];
  #pragma unroll
  for (int ksi = 0; ksi < 2; ksi++) {
    int c = (l >> 4) + ksi * 4;
    #pragma unroll
    for (int mt = 0; mt < 3; mt++) {
      int r = mt * 16 + (l & 15);
      pf[mt][ksi] = *(const s16x8*)(ksb + r * 128 + ((c ^ (r & 7)) * 16));
    }
    #pragma unroll
    for (int nt = 0; nt < 4; nt++) {
      int r = nt * 16 + (l & 15);
      vf[nt][ksi] = *(const s16x8*)(vtb + r * 128 + ((c ^ (r & 7)) * 16));
    }
  }
  f32x4 oacc[3][4];
  #pragma unroll
  for (int i = 0; i < 3; i++)
    #pragma unroll
    for (int j = 0; j < 4; j++)
      oacc[i][j] = (f32x4){0.f, 0.f, 0.f, 0.f};
  #pragma unroll
  for (int ksi = 0; ksi < 2; ksi++)
    #pragma unroll
    for (int mt = 0; mt < 3; mt++)
      #pragma unroll
      for (int nt = 0; nt < 4; nt++)
        oacc[mt][nt] = __builtin_amdgcn_mfma_f32_16x16x32_bf16(pf[mt][ksi], vf[nt][ksi], oacc[mt][nt], 0, 0, 0);

  #pragma unroll
  for (int mt = 0; mt < 3; mt++)
    #pragma unroll
    for (int nt = 0; nt < 4; nt++)
      #pragma unroll
      for (int rg = 0; rg < 4; rg++) {
        int t = mt * 16 + ((l >> 4) << 2) + rg;
        int m = mbase + t * NV;
        int col = head * 64 + nt * 16 + (l & 15);
        int ns = col ^ ((m & 7) << 3);
        obuf[(size_t)m * 512 + ns] = f2b(oacc[mt][nt][rg]);
      }
}

// ---------------------------------------------------------------------------
// K5: LayerNorm over F=512, wave per row, fp32 out
// ---------------------------------------------------------------------------
__global__ __launch_bounds__(256)
void ln_k(const unsigned short* __restrict__ h, const float* __restrict__ gamma,
          const float* __restrict__ beta, float* __restrict__ out)
{
  const int tid = threadIdx.x, l = tid & 63;
  const int m = blockIdx.x * 4 + (tid >> 6);
  const unsigned char* hb = (const unsigned char*)h;
  u32x4 raw = *(const u32x4*)(hb + (size_t)m * 1024 + ((l ^ (m & 7)) * 16));
  float f[8];
  float sum = 0.f, sq = 0.f;
  #pragma unroll
  for (int i = 0; i < 4; i++) {
    unsigned int u = raw[i];
    float a = __builtin_bit_cast(float, u << 16);
    float c = __builtin_bit_cast(float, u & 0xffff0000u);
    f[2 * i] = a; f[2 * i + 1] = c;
    sum += a + c; sq += a * a + c * c;
  }
  #pragma unroll
  for (int d = 1; d < 64; d <<= 1) { sum += __shfl_xor(sum, d, 64); sq += __shfl_xor(sq, d, 64); }
  float mean = sum * (1.0f / 512.0f);
  float var = sq * (1.0f / 512.0f) - mean * mean;
  float rs = rsqrtf(var + 1e-5f);
  int cb = l * 8;
  f32x4 o1, o2;
  #pragma unroll
  for (int j = 0; j < 4; j++) o1[j] = gamma[cb + j] * ((f[j] - mean) * rs) + beta[cb + j];
  #pragma unroll
  for (int j = 0; j < 4; j++) o2[j] = gamma[cb + 4 + j] * ((f[4 + j] - mean) * rs) + beta[cb + 4 + j];
  *(f32x4*)(out + (size_t)m * 512 + cb) = o1;
  *(f32x4*)(out + (size_t)m * 512 + cb + 4) = o2;
}

// ---------------------------------------------------------------------------
extern "C" void kernel_launch(void* const* d_in, const int* in_sizes, int n_in,
                              void* d_out, int out_size, void* d_ws, size_t ws_size,
                              hipStream_t stream)
{
  const float* x     = (const float*)d_in[0];
  const float* Wq    = (const float*)d_in[1];
  const float* bq    = (const float*)d_in[2];
  const float* Wk    = (const float*)d_in[3];
  const float* bk    = (const float*)d_in[4];
  const float* Wv    = (const float*)d_in[5];
  const float* bv    = (const float*)d_in[6];
  const float* W1    = (const float*)d_in[7];
  const float* b1    = (const float*)d_in[8];
  const float* W2    = (const float*)d_in[9];
  const float* b2    = (const float*)d_in[10];
  const float* gamma = (const float*)d_in[11];
  const float* beta  = (const float*)d_in[12];
  float* out = (float*)d_out;

  unsigned char* ws = (unsigned char*)d_ws;
  unsigned short* wqkv = (unsigned short*)ws;               // 1,572,864 B
  unsigned short* w1t  = (unsigned short*)(ws + 1572864);   //   524,288 B
  unsigned short* w2t  = (unsigned short*)(ws + 2097152);   //   524,288 B
  float*          bqkv = (float*)        (ws + 2621440);    //     6,144 B
  unsigned short* qkvb = (unsigned short*)(ws + 2627584);   // 488,374,272 B (also h1)
  unsigned short* obuf = (unsigned short*)(ws + 491001856); // 162,791,424 B (xb, then o/h2)

  unsigned short* xb = obuf;  // x bf16 lives only until attn overwrites obuf

  prep_weights<<<640, 256, 0, stream>>>(Wq, Wk, Wv, W1, W2, bq, bk, bv, wqkv, w1t, w2t, bqkv);
  // x fp32 -> bf16 swizzled rows (one-time cast; saves 12x fp32 re-read in QKV)
  xcast_k<<<MTOT / 4, 256, 0, stream>>>(x, xb);
  // QKV: [M,512] bf16 xb @ [512,1536] -> qkv bf16 (swz rows); grid 14904 = 8*1863
  gemm_k<0><<<1242 * 12, 256, 0, stream>>>((const void*)xb, wqkv, bqkv, nullptr, qkvb, 1536, 12);
  // attention -> o bf16 (swz rows; overwrites xb which is now dead)
  attn_k<<<3312 * 2, 256, 0, stream>>>(qkvb, obuf);
  // FFN1: gelu(o@W1+b1) -> h1 (aliases qkv region); grid 4968 = 8*621
  gemm_k<1><<<1242 * 4, 256, 0, stream>>>((const void*)obuf, w1t, b1, nullptr, qkvb, 512, 4);
  // FFN2: h1@W2+b2+x -> h2 (aliases o region)
  gemm_k<2><<<1242 * 4, 256, 0, stream>>>((const void*)qkvb, w2t, b2, x, obuf, 512, 4);
  // LayerNorm -> fp32 out
  ln_k<<<MTOT / 4, 256, 0, stream>>>(obuf, gamma, beta, out);
}